// Round 4
// baseline (113.276 us; speedup 1.0000x reference)
//
#include <hip/hip_runtime.h>

#define BOX   256
#define NCLS  2
#define BATCH 2
#define NPTS  262144                      // 2^18
#define VOL   (BOX * BOX * BOX)
#define NBINS (BATCH * BOX * BOX)         // (b, base_z, base_y) row-bins = 131072
#define CAP   32                          // records per bin (Poisson mean 4)
#define CAPSH 5
#define RY    16                          // rows per region tile
#define NT    (BOX / RY)                  // 16 y-tiles per plane
#define NREG  (BATCH * BOX * NT)          // 8192 region blocks
#define NBMETA 34                         // 2 planes x 17 rows per region

// ---------------------------------------------------------------------------
// Pass 0: zero the cursor array + overflow counter (contiguous 512KB + 256B).
// Replaces hipMemsetAsync: the runtime's fillBufferAligned path for this size
// profiled at 3.4 GB/s (~160 us) — a grid-stride float4 zero is ~2 us.
// ---------------------------------------------------------------------------
__global__ __launch_bounds__(256) void k_zero(float4* __restrict__ p, int n4)
{
    const int stride = gridDim.x * 256;
    for (int i = blockIdx.x * 256 + threadIdx.x; i < n4; i += stride)
        p[i] = make_float4(0.f, 0.f, 0.f, 0.f);
}

// ---------------------------------------------------------------------------
// Pass 1: one atomic per point -> slot in capacity-binned record array.
// Record = {px, pack16(ry,rz), v0, v1} (16 B). Overflow (essentially never:
// P[Poisson(4) > 32] ~ 1e-19) goes to a global list, handled correctly.
// ---------------------------------------------------------------------------
__global__ __launch_bounds__(256) void k_place(const float* __restrict__ pts,
                                               const float* __restrict__ vals,
                                               unsigned* __restrict__ cursor,
                                               float4* __restrict__ rec,
                                               float4* __restrict__ ovf4,
                                               unsigned* __restrict__ ovfbin,
                                               unsigned* __restrict__ ovfcnt)
{
    const int tid = blockIdx.x * 256 + threadIdx.x;   // exactly BATCH*NPTS threads
    const int b = tid >> 18;
    const int n = tid & (NPTS - 1);

    const float* pp = pts + ((size_t)b * NPTS + n) * 3;
    const float px = (pp[0] + 0.5f) * (float)BOX;
    const float py = (pp[1] + 0.5f) * (float)BOX;
    const float pz = (pp[2] + 0.5f) * (float)BOX;

    const float fy = floorf(py), fz = floorf(pz);
    const int by = (int)fy, bz = (int)fz;
    const float ry = py - fy, rz = pz - fz;

    // 16-bit fixed-point fractions (error <= 2^-16 per weight)
    const unsigned qy = (unsigned)(ry * 65536.0f);
    const unsigned qz = (unsigned)(rz * 65536.0f);
    const unsigned packed = (qz << 16) | (qy & 0xffffu);

    const float v0 = vals[((size_t)b * NCLS + 0) * NPTS + n];
    const float v1 = vals[((size_t)b * NCLS + 1) * NPTS + n];
    const float4 r = make_float4(px, __uint_as_float(packed), v0, v1);

    const unsigned bin = ((unsigned)b << 16) | ((unsigned)bz << 8) | (unsigned)by;
    const unsigned slot = atomicAdd(&cursor[bin], 1u);
    if (slot < CAP) {
        rec[((size_t)bin << CAPSH) + slot] = r;
    } else {
        const unsigned o = atomicAdd(ovfcnt, 1u);
        ovf4[o] = r;
        ovfbin[o] = bin;
    }
}

// ---------------------------------------------------------------------------
// Pass 2: one block per (b, z-plane P, y-tile T). Gather the 34 contributing
// row-bins (planes P-1,P x rows RY*T-1..RY*T+15), accumulate into a 32 KB
// LDS tile with LDS atomics, stream out coalesced float4 (full coverage ->
// no global zero-init of d_out needed).
// ---------------------------------------------------------------------------
__global__ __launch_bounds__(512) void k_region(const float4* __restrict__ rec,
                                                const unsigned* __restrict__ cursor,
                                                const float4* __restrict__ ovf4,
                                                const unsigned* __restrict__ ovfbin,
                                                const unsigned* __restrict__ ovfcnt,
                                                float* __restrict__ out)
{
    __shared__ float acc[NCLS * RY * BOX];      // 32 KB
    __shared__ unsigned s_bin[NBMETA];
    __shared__ unsigned s_len[NBMETA];
    __shared__ unsigned s_pfx[NBMETA + 1];

    const int tid = threadIdx.x;
    const int bid = blockIdx.x;
    const int b = bid >> 12;
    const int P = (bid >> 4) & 255;             // owned z-plane
    const int T = bid & 15;                     // owned y-tile (rows RY*T..RY*T+15)

    // zero tile: 8192 floats = 2048 float4 / 512 threads = 4 each
    {
        float4* a4 = (float4*)acc;
        #pragma unroll
        for (int i = 0; i < 4; ++i)
            a4[i * 512 + tid] = make_float4(0.f, 0.f, 0.f, 0.f);
    }

    // metadata: j in [0,34): zsrc = P-1 + (j>=17), row y0 = RY*T-1 + (j%17)
    if (tid < NBMETA) {
        const int j = tid;
        const int zsrc = P - 1 + (j >= 17 ? 1 : 0);
        const int y0 = RY * T - 1 + (j >= 17 ? j - 17 : j);
        unsigned bin = 0, len = 0;
        if (zsrc >= 0 && y0 >= 0 && y0 < BOX) {
            bin = ((unsigned)b << 16) | ((unsigned)zsrc << 8) | (unsigned)y0;
            len = cursor[bin];
            if (len > CAP) len = CAP;
        }
        s_bin[j] = bin;
        s_len[j] = len;
    }
    __syncthreads();

    // wave-parallel exclusive scan of s_len (first wave only)
    if (tid < 64) {
        const unsigned own = (tid < NBMETA) ? s_len[tid] : 0u;
        unsigned v = own;
        #pragma unroll
        for (int off = 1; off < 64; off <<= 1) {
            const unsigned t = __shfl_up(v, off, 64);
            if (tid >= off) v += t;
        }
        if (tid < NBMETA) s_pfx[tid] = v - own;
        if (tid == NBMETA - 1) s_pfx[NBMETA] = v;
    }
    __syncthreads();

    const int R = (int)s_pfx[NBMETA];
    for (int r = tid; r < R; r += 512) {
        // binary search: lo with s_pfx[lo] <= r < s_pfx[lo+1]
        int lo = 0, hi = NBMETA - 1;
        while (lo < hi) {
            const int mid = (lo + hi + 1) >> 1;
            if ((int)s_pfx[mid] <= r) lo = mid; else hi = mid - 1;
        }
        const size_t idx = ((size_t)s_bin[lo] << CAPSH) + (unsigned)(r - (int)s_pfx[lo]);
        const float4 q = rec[idx];

        const unsigned pk = __float_as_uint(q.y);
        const float ry = (float)(pk & 0xffffu) * (1.0f / 65536.0f);
        const float rz = (float)(pk >> 16) * (1.0f / 65536.0f);
        const float fx = floorf(q.x);
        const float rx = q.x - fx;
        const int ix = (int)fx;

        // lo>=17 -> record's base plane == P -> dz=0 corner weight (1-rz)
        const float wz = (lo >= 17) ? (1.0f - rz) : rz;
        const int yy0 = (lo >= 17 ? lo - 17 : lo) - 1;     // tile row for dy=0

        #pragma unroll
        for (int dy = 0; dy < 2; ++dy) {
            const int yy = yy0 + dy;
            if ((unsigned)yy < RY) {                        // excludes y==256 too
                const float wzy = wz * (dy ? ry : 1.0f - ry);
                #pragma unroll
                for (int dx = 0; dx < 2; ++dx) {
                    const int x = ix + dx;
                    if (x < BOX) {                          // excludes x==256
                        const float w = wzy * (dx ? rx : 1.0f - rx);
                        const int li = yy * BOX + x;
                        atomicAdd(&acc[li], w * q.z);
                        atomicAdd(&acc[RY * BOX + li], w * q.w);
                    }
                }
            }
        }
    }

    // overflow records (empty for this input; kept for correctness)
    const int oc = (int)*ovfcnt;
    for (int r = tid; r < oc; r += 512) {
        const unsigned bin = ovfbin[r];
        if ((int)(bin >> 16) != b) continue;
        const int bz = (int)((bin >> 8) & 255u);
        if (bz != P && bz != P - 1) continue;
        const int by = (int)(bin & 255u);
        const int yy0 = by - RY * T;
        if (yy0 < -1 || yy0 > RY - 1) continue;

        const float4 q = ovf4[r];
        const unsigned pk = __float_as_uint(q.y);
        const float ry = (float)(pk & 0xffffu) * (1.0f / 65536.0f);
        const float rz = (float)(pk >> 16) * (1.0f / 65536.0f);
        const float fx = floorf(q.x);
        const float rx = q.x - fx;
        const int ix = (int)fx;
        const float wz = (bz == P) ? (1.0f - rz) : rz;

        for (int dy = 0; dy < 2; ++dy) {
            const int yy = yy0 + dy;
            if ((unsigned)yy < RY) {
                const float wzy = wz * (dy ? ry : 1.0f - ry);
                for (int dx = 0; dx < 2; ++dx) {
                    const int x = ix + dx;
                    if (x < BOX) {
                        const float w = wzy * (dx ? rx : 1.0f - rx);
                        const int li = yy * BOX + x;
                        atomicAdd(&acc[li], w * q.z);
                        atomicAdd(&acc[RY * BOX + li], w * q.w);
                    }
                }
            }
        }
    }
    __syncthreads();

    // stream tile out: [b][c][P][RY*T..RY*T+15][:] — coalesced float4
    #pragma unroll
    for (int c = 0; c < NCLS; ++c) {
        const size_t o4base = (size_t)((b * NCLS + c) * BOX + P) * (BOX * BOX / 4)
                              + (size_t)T * (RY * BOX / 4);
        float4* o4 = (float4*)out;
        const float4* a4 = (const float4*)(acc + c * RY * BOX);
        #pragma unroll
        for (int i = 0; i < 2; ++i)
            o4[o4base + i * 512 + tid] = a4[i * 512 + tid];
    }
}

// ---------------------------------------------------------------------------
// Fallback: plain global-atomic scatter (only if ws too small).
// ---------------------------------------------------------------------------
__global__ __launch_bounds__(256) void cic_scatter_kernel(
    const float* __restrict__ points, const float* __restrict__ values,
    float* __restrict__ out)
{
    const int tid = blockIdx.x * blockDim.x + threadIdx.x;
    if (tid >= BATCH * NPTS) return;
    const int b = tid >> 18, n = tid & (NPTS - 1);
    const float* pp = points + ((size_t)b * NPTS + n) * 3;
    const float px = (pp[0] + 0.5f) * BOX, py = (pp[1] + 0.5f) * BOX, pz = (pp[2] + 0.5f) * BOX;
    const float fx = floorf(px), fy = floorf(py), fz = floorf(pz);
    const float rx = px - fx, ry = py - fy, rz = pz - fz;
    const int ix = (int)fx, iy = (int)fy, iz = (int)fz;
    const float v0 = values[((size_t)b * NCLS + 0) * NPTS + n];
    const float v1 = values[((size_t)b * NCLS + 1) * NPTS + n];
    const float wx[2] = {1.f - rx, rx}, wy[2] = {1.f - ry, ry}, wz[2] = {1.f - rz, rz};
    float* out0 = out + ((size_t)b * NCLS + 0) * (size_t)VOL;
    float* out1 = out + ((size_t)b * NCLS + 1) * (size_t)VOL;
    for (int dz = 0; dz < 2; ++dz) {
        const int z = iz + dz; if (z >= BOX) continue;
        for (int dy = 0; dy < 2; ++dy) {
            const int y = iy + dy; if (y >= BOX) continue;
            const float wzy = wz[dz] * wy[dy];
            const int rowbase = (z * BOX + y) * BOX;
            for (int dx = 0; dx < 2; ++dx) {
                const int x = ix + dx; if (x >= BOX) continue;
                atomicAdd(out0 + rowbase + x, wzy * wx[dx] * v0);
                atomicAdd(out1 + rowbase + x, wzy * wx[dx] * v1);
            }
        }
    }
}

extern "C" void kernel_launch(void* const* d_in, const int* in_sizes, int n_in,
                              void* d_out, int out_size, void* d_ws, size_t ws_size,
                              hipStream_t stream) {
    const float* points = (const float*)d_in[0];   // [B, N, 3]
    const float* values = (const float*)d_in[1];   // [B, C, N]
    float* out = (float*)d_out;                    // [B, C, 256,256,256]

    // ws layout (16B-aligned blocks)
    const size_t CUR_OFF  = 0;                                   // NBINS u32
    const size_t OVFC_OFF = (size_t)NBINS * 4;                   // 1 u32 (+pad)
    const size_t REC_OFF  = OVFC_OFF + 256;                      // NBINS*CAP float4
    const size_t OVF4_OFF = REC_OFF + (size_t)NBINS * CAP * 16;
    const size_t OVFB_OFF = OVF4_OFF + (size_t)BATCH * NPTS * 16;
    const size_t WS_NEED  = OVFB_OFF + (size_t)BATCH * NPTS * 4;

    if (ws_size < WS_NEED) {
        hipMemsetAsync(out, 0, (size_t)out_size * sizeof(float), stream);
        cic_scatter_kernel<<<(BATCH * NPTS) / 256, 256, 0, stream>>>(points, values, out);
        return;
    }

    char* ws = (char*)d_ws;
    unsigned* cursor = (unsigned*)(ws + CUR_OFF);
    unsigned* ovfcnt = (unsigned*)(ws + OVFC_OFF);
    float4*   rec    = (float4*)(ws + REC_OFF);
    float4*   ovf4   = (float4*)(ws + OVF4_OFF);
    unsigned* ovfbin = (unsigned*)(ws + OVFB_OFF);

    // zero cursors + overflow counter with our own kernel (fillBufferAligned
    // profiled at 3.4 GB/s for this size)
    const int n4 = (int)((OVFC_OFF + 256) / 16);   // 32784 float4s
    k_zero<<<256, 256, 0, stream>>>((float4*)ws, n4);

    k_place<<<(BATCH * NPTS) / 256, 256, 0, stream>>>(points, values, cursor,
                                                      rec, ovf4, ovfbin, ovfcnt);
    k_region<<<NREG, 512, 0, stream>>>(rec, cursor, ovf4, ovfbin, ovfcnt, out);
}